// Round 3
// baseline (1222.919 us; speedup 1.0000x reference)
//
#include <hip/hip_runtime.h>

#define NROWS 16384
#define KCB   8192
#define DIM   256
#define HW    1024

#define R_TILE  64
#define K_TILE  128
#define D_CHUNK 64
#define LDP (D_CHUNK + 4)   // 68 floats row stride

// workspace float offsets
#define WS_X2    0
#define WS_HVAL  NROWS                    // 2 halves * NROWS floats
#define WS_HIDX  (WS_HVAL + 2 * NROWS)    // 2 halves * NROWS ints
#define WS_LPART (WS_HIDX + 2 * NROWS)    // 256 floats

// ------- kernel 1: X[n] = numpy-pairwise sum of fl(x_d^2), d=0..255 -------
// numpy scalar pairwise for n=256: two 128-blocks; each: r[j]=a[j], then
// r[j]+=a[i+j] for i=8..120 step 8; combine ((r0+r1)+(r2+r3))+((r4+r5)+(r6+r7)).
__global__ __launch_bounds__(256) void vq_x2(const float* __restrict__ x,
                                             float* __restrict__ xsq) {
#pragma clang fp contract(off)
  const int n = blockIdx.x * 256 + threadIdx.x;
  const int b = n >> 10, hw = n & 1023;
  const float* xb = x + (size_t)b * (DIM * HW) + hw;
  float halves[2];
#pragma unroll
  for (int h = 0; h < 2; ++h) {
    float r[8];
#pragma unroll
    for (int j = 0; j < 8; ++j) {
      const float a = xb[(size_t)(h * 128 + j) * HW];
      r[j] = a * a;                       // separate mul rounding (contract off)
    }
    for (int i = 8; i < 128; i += 8) {
#pragma unroll
      for (int j = 0; j < 8; ++j) {
        const float a = xb[(size_t)(h * 128 + i + j) * HW];
        const float sq = a * a;
        r[j] = r[j] + sq;
      }
    }
    halves[h] = ((r[0] + r[1]) + (r[2] + r[3])) + ((r[4] + r[5]) + (r[6] + r[7]));
  }
  xsq[n] = halves[0] + halves[1];
}

// ------- kernel 2: fp32 split-K, emulate d = fl(X - 2*dot), per-half argmin -------
// dot accumulated as one sequential FMA chain in ascending d (matches BLAS
// micro-kernel accumulation). grid (256, 2): x = row tile, y = K half.
__global__ __launch_bounds__(256) void vq_main(const float* __restrict__ x,
                                               const float* __restrict__ emb,
                                               const float* __restrict__ xsq,
                                               float* __restrict__ hval,
                                               int* __restrict__ hidx) {
  __shared__ __align__(16) float x_lds[R_TILE][LDP];
  __shared__ __align__(16) float e_lds[K_TILE][LDP];

  const int t = threadIdx.x;
  const int tk = t & 31, tr = t >> 5;        // 32 x 8 thread grid
  const int bn = blockIdx.x, bh = blockIdx.y;
  const int n0 = bn * R_TILE;
  const int b = n0 >> 10, hw0 = n0 & 1023;
  const float* xb = x + (size_t)b * (DIM * HW) + hw0;

  const int lr = t & 63, lc = t >> 6;        // staging lane mapping

  float Xr[8];
#pragma unroll
  for (int i = 0; i < 8; ++i) Xr[i] = xsq[n0 + tr * 8 + i];

  float best_v[8];
  int   best_k[8];
#pragma unroll
  for (int i = 0; i < 8; ++i) { best_v[i] = 3.0e38f; best_k[i] = 0; }

  for (int kt = 0; kt < 32; ++kt) {
    const int kbase = (bh * 32 + kt) * K_TILE;
    float acc[8][4];
#pragma unroll
    for (int i = 0; i < 8; ++i)
#pragma unroll
      for (int j = 0; j < 4; ++j) acc[i][j] = 0.f;

    for (int dc = 0; dc < DIM / D_CHUNK; ++dc) {
      __syncthreads();
#pragma unroll
      for (int it = 0; it < 16; ++it) {
        int dd = lc + 4 * it;
        x_lds[lr][dd] = xb[(size_t)(dc * D_CHUNK + dd) * HW + lr];
      }
#pragma unroll
      for (int it = 0; it < 32; ++it) {
        int kk = lc + 4 * it;
        e_lds[kk][lr] = emb[(size_t)(kbase + kk) * DIM + dc * D_CHUNK + lr];
      }
      __syncthreads();

#pragma unroll 2
      for (int d4 = 0; d4 < D_CHUNK; d4 += 4) {
        float4 e4[4];
#pragma unroll
        for (int j = 0; j < 4; ++j)
          e4[j] = *(const float4*)&e_lds[tk + 32 * j][d4];
#pragma unroll
        for (int i = 0; i < 8; ++i) {
          float4 x4 = *(const float4*)&x_lds[tr * 8 + i][d4];
#pragma unroll
          for (int j = 0; j < 4; ++j) {
            acc[i][j] = fmaf(x4.x, e4[j].x, acc[i][j]);
            acc[i][j] = fmaf(x4.y, e4[j].y, acc[i][j]);
            acc[i][j] = fmaf(x4.z, e4[j].z, acc[i][j]);
            acc[i][j] = fmaf(x4.w, e4[j].w, acc[i][j]);
          }
        }
      }
    }

    // fold: s = fl(X - 2*acc)  (2*acc exact; one rounded subtract = numpy's)
    // kg ascending within thread, strict < keeps first occurrence.
#pragma unroll
    for (int j = 0; j < 4; ++j) {
      const int kg = kbase + tk + 32 * j;
#pragma unroll
      for (int i = 0; i < 8; ++i) {
        const float s = Xr[i] - 2.0f * acc[i][j];
        if (s < best_v[i]) { best_v[i] = s; best_k[i] = kg; }
      }
    }
  }

  // cross-thread reduction: 32 (v,k) pairs per row -> lowest-k-on-tie min
  __syncthreads();
  float* rv = &x_lds[0][0];              // 64 rows * stride 33 = 2112 <= 4352
  int*   ri = (int*)&e_lds[0][0];
#pragma unroll
  for (int i = 0; i < 8; ++i) {
    const int r = tr * 8 + i;
    rv[r * 33 + tk] = best_v[i];
    ri[r * 33 + tk] = best_k[i];
  }
  __syncthreads();
  if (t < R_TILE) {
    float bv = rv[t * 33];
    int   bk = ri[t * 33];
    for (int m = 1; m < 32; ++m) {
      const float v = rv[t * 33 + m];
      const int   k = ri[t * 33 + m];
      if (v < bv || (v == bv && k < bk)) { bv = v; bk = k; }
    }
    hval[bh * NROWS + n0 + t] = bv;
    hidx[bh * NROWS + n0 + t] = bk;
  }
}

// ------- kernel 3: merge halves -> idx, gather q, straight-through out, loss -------
__global__ __launch_bounds__(256) void vq_epi(const float* __restrict__ x,
                                              const float* __restrict__ emb,
                                              const float* __restrict__ hval,
                                              const int* __restrict__ hidx,
                                              float* __restrict__ out_q,
                                              float* __restrict__ out_idx,
                                              float* __restrict__ lpart) {
  __shared__ int bestk_sh[R_TILE];
  __shared__ float wsum[4];
  const int t = threadIdx.x;
  const int n0 = blockIdx.x * R_TILE;
  const int b = n0 >> 10, hw0 = n0 & 1023;

  if (t < R_TILE) {
    const int n = n0 + t;
    const float v0 = hval[n], v1 = hval[NROWS + n];
    const int k0 = hidx[n], k1 = hidx[NROWS + n];
    const int bk = (v1 < v0) ? k1 : k0;  // tie -> half 0 (strictly lower k)
    bestk_sh[t] = bk;
    out_idx[n] = (float)bk;
  }
  __syncthreads();

  const int er = t & 63, dg = t >> 6;
  const int ks = bestk_sh[er];
  const float* eq = emb + (size_t)ks * DIM;
  const float* xb = x + (size_t)b * (DIM * HW) + hw0 + er;
  float* ob = out_q + (size_t)b * (DIM * HW) + hw0 + er;
  float lacc = 0.f;
#pragma unroll 4
  for (int it = 0; it < 64; ++it) {
    const int d = dg + 4 * it;
    const float qv = eq[d];
    const float xv = xb[(size_t)d * HW];
    ob[(size_t)d * HW] = qv;
    const float df = qv - xv;
    lacc = fmaf(df, df, lacc);
  }
#pragma unroll
  for (int off = 32; off > 0; off >>= 1) lacc += __shfl_down(lacc, off, 64);
  if ((t & 63) == 0) wsum[t >> 6] = lacc;
  __syncthreads();
  if (t == 0) lpart[blockIdx.x] = wsum[0] + wsum[1] + wsum[2] + wsum[3];
}

// ------- kernel 4: loss = 1.25 * mean((q-x)^2) -------
__global__ __launch_bounds__(256) void vq_loss(const float* __restrict__ lpart,
                                               float* __restrict__ out_loss) {
  __shared__ double dsum[4];
  const int t = threadIdx.x;
  double s = (double)lpart[t];
#pragma unroll
  for (int off = 32; off > 0; off >>= 1) s += __shfl_down(s, off, 64);
  if ((t & 63) == 0) dsum[t >> 6] = s;
  __syncthreads();
  if (t == 0) {
    const double total = dsum[0] + dsum[1] + dsum[2] + dsum[3];
    out_loss[0] = (float)(total * 1.25 / 4194304.0);
  }
}

extern "C" void kernel_launch(void* const* d_in, const int* in_sizes, int n_in,
                              void* d_out, int out_size, void* d_ws, size_t ws_size,
                              hipStream_t stream) {
  const float* x   = (const float*)d_in[0];   // [16,256,32,32]
  const float* emb = (const float*)d_in[1];   // [8192,256]
  float* out = (float*)d_out;
  float* ws  = (float*)d_ws;

  float* xsq   = ws + WS_X2;
  float* hval  = ws + WS_HVAL;
  int*   hidx  = (int*)(ws + WS_HIDX);
  float* lpart = ws + WS_LPART;

  float* out_q    = out;               // 4194304 floats
  float* out_loss = out + 4194304;     // 1 float
  float* out_idx  = out + 4194305;     // 16384 floats

  vq_x2<<<NROWS / 256, 256, 0, stream>>>(x, xsq);
  vq_main<<<dim3(NROWS / R_TILE, 2), 256, 0, stream>>>(x, emb, xsq, hval, hidx);
  vq_epi<<<NROWS / R_TILE, 256, 0, stream>>>(x, emb, hval, hidx, out_q, out_idx, lpart);
  vq_loss<<<1, 256, 0, stream>>>(lpart, out_loss);
}

// Round 4
// 476.873 us; speedup vs baseline: 2.5645x; 2.5645x over previous
//
#include <hip/hip_runtime.h>

#define NROWS 16384
#define KCB   8192
#define DIM   256
#define HW    1024

typedef __attribute__((ext_vector_type(8))) short  bf16x8;
typedef __attribute__((ext_vector_type(4))) float  f32x4;

// ---- workspace float offsets ----
#define WS_XSQ   0                         // 16384 f
#define WS_XT    16384                     // 16384*256 f  (x transposed, fp32, rows contiguous)
#define WS_XB    (WS_XT + 4194304)         // 16384*256 bf16 -> 2097152 float slots
#define WS_EB    (WS_XB + 2097152)         // 8192*256 bf16  -> 1048576 float slots
#define WS_BMAX  (WS_EB + 1048576)         // 128 * 16384 f  (per 64-col block, per row: max dot)
#define WS_BESTK (WS_BMAX + 2097152)       // 16384 int
#define WS_LPART (WS_BESTK + 16384)        // 256 f
// total ~9.47M floats = 37.9 MB

#define GLD_LDS(g, l) __builtin_amdgcn_global_load_lds( \
    (const __attribute__((address_space(1))) void*)(g), \
    (__attribute__((address_space(3))) void*)(l), 16, 0, 0)

__device__ inline unsigned short f2bf(float v) {
  unsigned u = __float_as_uint(v);
  unsigned r = (u + 0x7FFFu + ((u >> 16) & 1u)) >> 16;
  return (unsigned short)r;
}

// ------- kernel 1: X[n] = numpy-pairwise sum of fl(x_d^2) (UNCHANGED, passed) -------
__global__ __launch_bounds__(256) void vq_x2(const float* __restrict__ x,
                                             float* __restrict__ xsq) {
#pragma clang fp contract(off)
  const int n = blockIdx.x * 256 + threadIdx.x;
  const int b = n >> 10, hw = n & 1023;
  const float* xb = x + (size_t)b * (DIM * HW) + hw;
  float halves[2];
#pragma unroll
  for (int h = 0; h < 2; ++h) {
    float r[8];
#pragma unroll
    for (int j = 0; j < 8; ++j) {
      const float a = xb[(size_t)(h * 128 + j) * HW];
      r[j] = a * a;
    }
    for (int i = 8; i < 128; i += 8) {
#pragma unroll
      for (int j = 0; j < 8; ++j) {
        const float a = xb[(size_t)(h * 128 + i + j) * HW];
        const float sq = a * a;
        r[j] = r[j] + sq;
      }
    }
    halves[h] = ((r[0] + r[1]) + (r[2] + r[3])) + ((r[4] + r[5]) + (r[6] + r[7]));
  }
  xsq[n] = halves[0] + halves[1];
}

// ------- kernel 2: transpose x -> xT fp32 [N][D] and xb bf16 [N][D] -------
// grid (16 b, 4 d-tiles, 16 hw-tiles), 256 threads; LDS tile 64x64, pad 67 (bank-clean)
__global__ __launch_bounds__(256) void vq_cvt_x(const float* __restrict__ x,
                                                float* __restrict__ xT,
                                                unsigned short* __restrict__ xb) {
  __shared__ float lds[64 * 67];
  const int t = threadIdx.x, w = t >> 6;
  const int b = blockIdx.x, d0 = blockIdx.y * 64, hw0 = blockIdx.z * 64;
#pragma unroll
  for (int it = 0; it < 16; ++it) {
    const int d_loc = it * 4 + w, hw_loc = t & 63;
    lds[d_loc * 67 + hw_loc] =
        x[((size_t)(b * DIM + d0 + d_loc)) * HW + hw0 + hw_loc];
  }
  __syncthreads();
#pragma unroll
  for (int it = 0; it < 16; ++it) {
    const int hw_loc = it * 4 + w, d_loc = t & 63;
    const float v = lds[d_loc * 67 + hw_loc];
    const size_t n = (size_t)b * HW + hw0 + hw_loc;
    xT[n * DIM + d0 + d_loc] = v;
    xb[n * DIM + d0 + d_loc] = f2bf(v);
  }
}

// ------- kernel 3: emb fp32 -> bf16 (elementwise) -------
__global__ __launch_bounds__(256) void vq_cvt_e(const float* __restrict__ emb,
                                                unsigned short* __restrict__ eb) {
  const int i = (blockIdx.x * 256 + threadIdx.x) * 4;
  const float4 v = *(const float4*)&emb[i];
  ushort4 o;
  o.x = f2bf(v.x); o.y = f2bf(v.y); o.z = f2bf(v.z); o.w = f2bf(v.w);
  *(ushort4*)&eb[i] = o;
}

// ------- kernel 4: bf16 MFMA coarse GEMM; per (row, 64-col wave block) max dot -------
// m97 recipe: 128x128 tile, BK=64, global_load_lds w16, 16x16x32 bf16.
// grid (128 row-tiles, 64 col-tiles), 256 threads = 4 waves (2x2).
__global__ __launch_bounds__(256) void vq_coarse(const unsigned short* __restrict__ xb,
                                                 const unsigned short* __restrict__ eb,
                                                 float* __restrict__ bmax) {
  __shared__ __align__(16) unsigned short a_lds[128 * 64];
  __shared__ __align__(16) unsigned short b_lds[128 * 64];
  const int t = threadIdx.x, lane = t & 63, w = t >> 6;
  const int wr = w >> 1, wc = w & 1;
  const int row0 = blockIdx.x * 128, col0 = blockIdx.y * 128;
  const int q = lane >> 4, l15 = lane & 15;
  const int srow = lane >> 3, scol = (lane & 7) * 8;   // staging lane map (8B bf16 = 16B)

  f32x4 acc[4][4];
#pragma unroll
  for (int i = 0; i < 4; ++i)
#pragma unroll
    for (int j = 0; j < 4; ++j) acc[i][j] = (f32x4){0.f, 0.f, 0.f, 0.f};

  for (int kc = 0; kc < 4; ++kc) {
    const int k0 = kc * 64;
    __syncthreads();
#pragma unroll
    for (int c = 0; c < 4; ++c) {
      const int rbase = c * 32 + w * 8;
      GLD_LDS(xb + (size_t)(row0 + rbase + srow) * DIM + k0 + scol, &a_lds[rbase * 64]);
      GLD_LDS(eb + (size_t)(col0 + rbase + srow) * DIM + k0 + scol, &b_lds[rbase * 64]);
    }
    __syncthreads();
#pragma unroll
    for (int s = 0; s < 2; ++s) {
      bf16x8 af[4], bfr[4];
#pragma unroll
      for (int i = 0; i < 4; ++i)
        af[i] = *(const bf16x8*)&a_lds[(wr * 64 + i * 16 + l15) * 64 + s * 32 + q * 8];
#pragma unroll
      for (int j = 0; j < 4; ++j)
        bfr[j] = *(const bf16x8*)&b_lds[(wc * 64 + j * 16 + l15) * 64 + s * 32 + q * 8];
#pragma unroll
      for (int i = 0; i < 4; ++i)
#pragma unroll
        for (int j = 0; j < 4; ++j)
          acc[i][j] = __builtin_amdgcn_mfma_f32_16x16x32_bf16(af[i], bfr[j], acc[i][j], 0, 0, 0);
    }
  }

  // epilogue: per row (C layout: col=lane&15, row=q*4+reg), max over wave's 64 cols
#pragma unroll
  for (int i = 0; i < 4; ++i) {
#pragma unroll
    for (int r = 0; r < 4; ++r) {
      float m = fmaxf(fmaxf(acc[i][0][r], acc[i][1][r]),
                      fmaxf(acc[i][2][r], acc[i][3][r]));
#pragma unroll
      for (int off = 1; off < 16; off <<= 1)
        m = fmaxf(m, __shfl_xor(m, off, 64));
      if (l15 == 0) {
        const int rowg = row0 + wr * 64 + i * 16 + q * 4 + r;
        bmax[(size_t)(blockIdx.y * 2 + wc) * NROWS + rowg] = m;
      }
    }
  }
}

// ------- kernel 5: per-row candidate blocks + EXACT fp32-chain refine -------
// one wave per row; candidate 64-col blocks where blockmax >= rowmax - DELTA;
// each lane re-scores one column with the bit-exact round-3 chain.
#define DELTA 5.0e-5f
__global__ __launch_bounds__(256) void vq_select(const float* __restrict__ xT,
                                                 const float* __restrict__ emb,
                                                 const float* __restrict__ xsq,
                                                 const float* __restrict__ bmax,
                                                 int* __restrict__ bestk,
                                                 float* __restrict__ out_idx) {
  const int t = threadIdx.x, lane = t & 63, w = t >> 6;
  const int n = blockIdx.x * 4 + w;

  const float v0 = bmax[(size_t)lane * NROWS + n];
  const float v1 = bmax[(size_t)(64 + lane) * NROWS + n];
  float m = fmaxf(v0, v1);
#pragma unroll
  for (int off = 1; off < 64; off <<= 1) m = fmaxf(m, __shfl_xor(m, off, 64));
  const float thr = m - DELTA;
  unsigned long long mask0 = __ballot(v0 >= thr);
  unsigned long long mask1 = __ballot(v1 >= thr);

  const float X = xsq[n];
  const float* xr = xT + (size_t)n * DIM;
  float bv = 3.0e38f;
  int bk = 0x7fffffff;

  unsigned long long mm = mask0;
  int base = 0;
#pragma unroll
  for (int half = 0; half < 2; ++half) {
    while (mm) {
      const int c = __builtin_ctzll(mm);
      mm &= mm - 1;
      const int k = (base + c) * 64 + lane;
      const float* er = emb + (size_t)k * DIM;
      float acc = 0.f;
#pragma unroll 8
      for (int d = 0; d < DIM; ++d) acc = fmaf(xr[d], er[d], acc);
      const float s = X - 2.0f * acc;     // identical rounding to round-3 chain
      if (s < bv || (s == bv && k < bk)) { bv = s; bk = k; }
    }
    mm = mask1;
    base = 64;
  }

#pragma unroll
  for (int off = 1; off < 64; off <<= 1) {
    const float ov = __shfl_xor(bv, off, 64);
    const int   ok = __shfl_xor(bk, off, 64);
    if (ov < bv || (ov == bv && ok < bk)) { bv = ov; bk = ok; }
  }
  if (lane == 0) { bestk[n] = bk; out_idx[n] = (float)bk; }
}

// ------- kernel 6: gather q, straight-through out, loss partials -------
__global__ __launch_bounds__(256) void vq_epi(const float* __restrict__ x,
                                              const float* __restrict__ emb,
                                              const int* __restrict__ bestk,
                                              float* __restrict__ out_q,
                                              float* __restrict__ lpart) {
  __shared__ int bestk_sh[64];
  __shared__ float wsum[4];
  const int t = threadIdx.x;
  const int n0 = blockIdx.x * 64;
  const int b = n0 >> 10, hw0 = n0 & 1023;

  if (t < 64) bestk_sh[t] = bestk[n0 + t];
  __syncthreads();

  const int er = t & 63, dg = t >> 6;
  const int ks = bestk_sh[er];
  const float* eq = emb + (size_t)ks * DIM;
  const float* xb = x + (size_t)b * (DIM * HW) + hw0 + er;
  float* ob = out_q + (size_t)b * (DIM * HW) + hw0 + er;
  float lacc = 0.f;
#pragma unroll 4
  for (int it = 0; it < 64; ++it) {
    const int d = dg + 4 * it;
    const float qv = eq[d];
    const float xv = xb[(size_t)d * HW];
    ob[(size_t)d * HW] = qv;
    const float df = qv - xv;
    lacc = fmaf(df, df, lacc);
  }
#pragma unroll
  for (int off = 32; off > 0; off >>= 1) lacc += __shfl_down(lacc, off, 64);
  if ((t & 63) == 0) wsum[t >> 6] = lacc;
  __syncthreads();
  if (t == 0) lpart[blockIdx.x] = wsum[0] + wsum[1] + wsum[2] + wsum[3];
}

// ------- kernel 7: loss = 1.25 * mean((q-x)^2) -------
__global__ __launch_bounds__(256) void vq_loss(const float* __restrict__ lpart,
                                               float* __restrict__ out_loss) {
  __shared__ double dsum[4];
  const int t = threadIdx.x;
  double s = (double)lpart[t];
#pragma unroll
  for (int off = 32; off > 0; off >>= 1) s += __shfl_down(s, off, 64);
  if ((t & 63) == 0) dsum[t >> 6] = s;
  __syncthreads();
  if (t == 0) {
    const double total = dsum[0] + dsum[1] + dsum[2] + dsum[3];
    out_loss[0] = (float)(total * 1.25 / 4194304.0);
  }
}

extern "C" void kernel_launch(void* const* d_in, const int* in_sizes, int n_in,
                              void* d_out, int out_size, void* d_ws, size_t ws_size,
                              hipStream_t stream) {
  const float* x   = (const float*)d_in[0];   // [16,256,32,32]
  const float* emb = (const float*)d_in[1];   // [8192,256]
  float* out = (float*)d_out;
  float* ws  = (float*)d_ws;

  float*          xsq   = ws + WS_XSQ;
  float*          xT    = ws + WS_XT;
  unsigned short* xb    = (unsigned short*)(ws + WS_XB);
  unsigned short* eb    = (unsigned short*)(ws + WS_EB);
  float*          bmax  = ws + WS_BMAX;
  int*            bestk = (int*)(ws + WS_BESTK);
  float*          lpart = ws + WS_LPART;

  float* out_q    = out;               // 4194304 floats
  float* out_loss = out + 4194304;     // 1 float
  float* out_idx  = out + 4194305;     // 16384 floats

  vq_x2<<<NROWS / 256, 256, 0, stream>>>(x, xsq);
  vq_cvt_x<<<dim3(16, 4, 16), 256, 0, stream>>>(x, xT, xb);
  vq_cvt_e<<<(KCB * DIM) / 1024, 256, 0, stream>>>(emb, eb);
  vq_coarse<<<dim3(NROWS / 128, KCB / 128), 256, 0, stream>>>(xb, eb, bmax);
  vq_select<<<NROWS / 4, 256, 0, stream>>>(xT, emb, xsq, bmax, bestk, out_idx);
  vq_epi<<<NROWS / 64, 256, 0, stream>>>(x, emb, bestk, out_q, lpart);
  vq_loss<<<1, 256, 0, stream>>>(lpart, out_loss);
}

// Round 5
// 472.368 us; speedup vs baseline: 2.5889x; 1.0095x over previous
//
#include <hip/hip_runtime.h>
#include <hip/hip_fp16.h>

#define NROWS 16384
#define KCB   8192
#define DIM   256
#define HW    1024

typedef __attribute__((ext_vector_type(8))) short  bf16x8;
typedef __attribute__((ext_vector_type(4))) float  f32x4;

// ---- workspace float offsets ----
#define WS_XSQ   0                         // 16384 f
#define WS_XT    16384                     // 16384*256 f (x row-major fp32)
#define WS_XB    (WS_XT + 4194304)         // bf16 x -> 2097152 f slots
#define WS_EB    (WS_XB + 2097152)         // bf16 emb -> 1048576 f slots
#define WS_TMAX  (WS_EB + 1048576)         // fp16 [512 tiles][16384 rows] -> 4194304 f slots
#define WS_BESTK (WS_TMAX + 4194304)       // 16384 int
#define WS_LPART (WS_BESTK + 16384)        // 256 f
// total ~11.57M floats = 46.3 MB

#define GLD_LDS(g, l) __builtin_amdgcn_global_load_lds( \
    (const __attribute__((address_space(1))) void*)(g), \
    (__attribute__((address_space(3))) void*)(l), 16, 0, 0)

__device__ inline unsigned short f2bf(float v) {
  unsigned u = __float_as_uint(v);
  unsigned r = (u + 0x7FFFu + ((u >> 16) & 1u)) >> 16;
  return (unsigned short)r;
}

// ------- kernel 1: X[n] = numpy-pairwise sum of fl(x_d^2) (UNCHANGED, passed) -------
__global__ __launch_bounds__(256) void vq_x2(const float* __restrict__ x,
                                             float* __restrict__ xsq) {
#pragma clang fp contract(off)
  const int n = blockIdx.x * 256 + threadIdx.x;
  const int b = n >> 10, hw = n & 1023;
  const float* xb = x + (size_t)b * (DIM * HW) + hw;
  float halves[2];
#pragma unroll
  for (int h = 0; h < 2; ++h) {
    float r[8];
#pragma unroll
    for (int j = 0; j < 8; ++j) {
      const float a = xb[(size_t)(h * 128 + j) * HW];
      r[j] = a * a;
    }
    for (int i = 8; i < 128; i += 8) {
#pragma unroll
      for (int j = 0; j < 8; ++j) {
        const float a = xb[(size_t)(h * 128 + i + j) * HW];
        const float sq = a * a;
        r[j] = r[j] + sq;
      }
    }
    halves[h] = ((r[0] + r[1]) + (r[2] + r[3])) + ((r[4] + r[5]) + (r[6] + r[7]));
  }
  xsq[n] = halves[0] + halves[1];
}

// ------- kernel 2: transpose x -> xT fp32 [N][D] + xb bf16 [N][D] (UNCHANGED) -------
__global__ __launch_bounds__(256) void vq_cvt_x(const float* __restrict__ x,
                                                float* __restrict__ xT,
                                                unsigned short* __restrict__ xb) {
  __shared__ float lds[64 * 67];
  const int t = threadIdx.x, w = t >> 6;
  const int b = blockIdx.x, d0 = blockIdx.y * 64, hw0 = blockIdx.z * 64;
#pragma unroll
  for (int it = 0; it < 16; ++it) {
    const int d_loc = it * 4 + w, hw_loc = t & 63;
    lds[d_loc * 67 + hw_loc] =
        x[((size_t)(b * DIM + d0 + d_loc)) * HW + hw0 + hw_loc];
  }
  __syncthreads();
#pragma unroll
  for (int it = 0; it < 16; ++it) {
    const int hw_loc = it * 4 + w, d_loc = t & 63;
    const float v = lds[d_loc * 67 + hw_loc];
    const size_t n = (size_t)b * HW + hw0 + hw_loc;
    xT[n * DIM + d0 + d_loc] = v;
    xb[n * DIM + d0 + d_loc] = f2bf(v);
  }
}

// ------- kernel 3: emb fp32 -> bf16 (UNCHANGED) -------
__global__ __launch_bounds__(256) void vq_cvt_e(const float* __restrict__ emb,
                                                unsigned short* __restrict__ eb) {
  const int i = (blockIdx.x * 256 + threadIdx.x) * 4;
  const float4 v = *(const float4*)&emb[i];
  ushort4 o;
  o.x = f2bf(v.x); o.y = f2bf(v.y); o.z = f2bf(v.z); o.w = f2bf(v.w);
  *(ushort4*)&eb[i] = o;
}

// ------- kernel 4: bf16 MFMA coarse GEMM; per (row, 16-col tile) max -> fp16 -------
// MFMA core identical to round 4 (verified). 1D grid 8192, XCD-partitioned decode:
// lin&7 = XCD slot -> 16-row-tile slice (1 MB A, L2-resident), col-tile-major within.
__global__ __launch_bounds__(256) void vq_coarse(const unsigned short* __restrict__ xb,
                                                 const unsigned short* __restrict__ eb,
                                                 __half* __restrict__ tmax) {
  __shared__ __align__(16) unsigned short a_lds[128 * 64];
  __shared__ __align__(16) unsigned short b_lds[128 * 64];
  const int lin = blockIdx.x;
  const int xcd = lin & 7;
  const int s_  = lin >> 3;
  const int row_t = xcd * 16 + (s_ & 15);    // 0..127
  const int col_t = s_ >> 4;                 // 0..63
  const int t = threadIdx.x, lane = t & 63, w = t >> 6;
  const int wr = w >> 1, wc = w & 1;
  const int row0 = row_t * 128, col0 = col_t * 128;
  const int q = lane >> 4, l15 = lane & 15;
  const int srow = lane >> 3, scol = (lane & 7) * 8;

  f32x4 acc[4][4];
#pragma unroll
  for (int i = 0; i < 4; ++i)
#pragma unroll
    for (int j = 0; j < 4; ++j) acc[i][j] = (f32x4){0.f, 0.f, 0.f, 0.f};

  for (int kc = 0; kc < 4; ++kc) {
    const int k0 = kc * 64;
    __syncthreads();
#pragma unroll
    for (int c = 0; c < 4; ++c) {
      const int rbase = c * 32 + w * 8;
      GLD_LDS(xb + (size_t)(row0 + rbase + srow) * DIM + k0 + scol, &a_lds[rbase * 64]);
      GLD_LDS(eb + (size_t)(col0 + rbase + srow) * DIM + k0 + scol, &b_lds[rbase * 64]);
    }
    __syncthreads();
#pragma unroll
    for (int s = 0; s < 2; ++s) {
      bf16x8 af[4], bfr[4];
#pragma unroll
      for (int i = 0; i < 4; ++i)
        af[i] = *(const bf16x8*)&a_lds[(wr * 64 + i * 16 + l15) * 64 + s * 32 + q * 8];
#pragma unroll
      for (int j = 0; j < 4; ++j)
        bfr[j] = *(const bf16x8*)&b_lds[(wc * 64 + j * 16 + l15) * 64 + s * 32 + q * 8];
#pragma unroll
      for (int i = 0; i < 4; ++i)
#pragma unroll
        for (int j = 0; j < 4; ++j)
          acc[i][j] = __builtin_amdgcn_mfma_f32_16x16x32_bf16(af[i], bfr[j], acc[i][j], 0, 0, 0);
    }
  }

  // epilogue: C layout col=l15, row=q*4+r. Per (i,j,r): max over 16 cols (l15 group).
#pragma unroll
  for (int i = 0; i < 4; ++i)
#pragma unroll
    for (int j = 0; j < 4; ++j) {
      const int tile = col_t * 8 + wc * 4 + j;
#pragma unroll
      for (int r = 0; r < 4; ++r) {
        float m = acc[i][j][r];
        m = fmaxf(m, __shfl_xor(m, 1, 64));
        m = fmaxf(m, __shfl_xor(m, 2, 64));
        m = fmaxf(m, __shfl_xor(m, 4, 64));
        m = fmaxf(m, __shfl_xor(m, 8, 64));
        if (l15 == 0) {
          const int rowg = row0 + wr * 64 + i * 16 + q * 4 + r;
          tmax[(size_t)tile * NROWS + rowg] = __float2half(m);
        }
      }
    }
}

// ------- kernel 5: per-row qualifying 16-col tiles + EXACT fp32-chain refine -------
#define DELTA 1.0e-4f
__global__ __launch_bounds__(256) void vq_select(const float* __restrict__ xT,
                                                 const float* __restrict__ emb,
                                                 const float* __restrict__ xsq,
                                                 const __half* __restrict__ tmax,
                                                 int* __restrict__ bestk,
                                                 float* __restrict__ out_idx) {
  __shared__ int tl_sh[4][16];
  const int t = threadIdx.x, lane = t & 63, w = t >> 6;
  const int n = blockIdx.x * 4 + w;

  float tv[8];
#pragma unroll
  for (int u = 0; u < 8; ++u)
    tv[u] = __half2float(tmax[(size_t)(lane + 64 * u) * NROWS + n]);
  float m = tv[0];
#pragma unroll
  for (int u = 1; u < 8; ++u) m = fmaxf(m, tv[u]);
#pragma unroll
  for (int off = 1; off < 64; off <<= 1) m = fmaxf(m, __shfl_xor(m, off, 64));
  const float thr = m - DELTA;

  // wave-uniform candidate tile list (all lanes run identical code; benign LDS race)
  int count = 0;
#pragma unroll
  for (int u = 0; u < 8; ++u) {
    unsigned long long mask = __ballot(tv[u] >= thr);
    while (mask) {
      const int b = __builtin_ctzll(mask);
      mask &= mask - 1;
      if (count < 16) tl_sh[w][count] = b + 64 * u;
      ++count;
    }
  }
  if (count > 16) count = 16;

  const float X = xsq[n];
  const float* xr = xT + (size_t)n * DIM;
  float bv = 3.0e38f;
  int bk = 0x7fffffff;

  for (int g = 0; g < count; g += 4) {
    const int nt = (count - g < 4) ? (count - g) : 4;
    const int slot = lane >> 4;
    const int tile = tl_sh[w][g + ((slot < nt) ? slot : 0)];
    const int k = tile * 16 + (lane & 15);
    const float* er = emb + (size_t)k * DIM;
    float acc = 0.f;
#pragma unroll 16
    for (int d = 0; d < DIM; ++d) acc = fmaf(xr[d], er[d], acc);  // exact numpy chain
    const float sc = X - 2.0f * acc;
    if (sc < bv || (sc == bv && k < bk)) { bv = sc; bk = k; }
  }

#pragma unroll
  for (int off = 1; off < 64; off <<= 1) {
    const float ov = __shfl_xor(bv, off, 64);
    const int   ok = __shfl_xor(bk, off, 64);
    if (ov < bv || (ov == bv && ok < bk)) { bv = ov; bk = ok; }
  }
  if (lane == 0) { bestk[n] = bk; out_idx[n] = (float)bk; }
}

// ------- kernel 6: gather q, straight-through out, loss partials (UNCHANGED) -------
__global__ __launch_bounds__(256) void vq_epi(const float* __restrict__ x,
                                              const float* __restrict__ emb,
                                              const int* __restrict__ bestk,
                                              float* __restrict__ out_q,
                                              float* __restrict__ lpart) {
  __shared__ int bestk_sh[64];
  __shared__ float wsum[4];
  const int t = threadIdx.x;
  const int n0 = blockIdx.x * 64;
  const int b = n0 >> 10, hw0 = n0 & 1023;

  if (t < 64) bestk_sh[t] = bestk[n0 + t];
  __syncthreads();

  const int er = t & 63, dg = t >> 6;
  const int ks = bestk_sh[er];
  const float* eq = emb + (size_t)ks * DIM;
  const float* xb = x + (size_t)b * (DIM * HW) + hw0 + er;
  float* ob = out_q + (size_t)b * (DIM * HW) + hw0 + er;
  float lacc = 0.f;
#pragma unroll 4
  for (int it = 0; it < 64; ++it) {
    const int d = dg + 4 * it;
    const float qv = eq[d];
    const float xv = xb[(size_t)d * HW];
    ob[(size_t)d * HW] = qv;
    const float df = qv - xv;
    lacc = fmaf(df, df, lacc);
  }
#pragma unroll
  for (int off = 32; off > 0; off >>= 1) lacc += __shfl_down(lacc, off, 64);
  if ((t & 63) == 0) wsum[t >> 6] = lacc;
  __syncthreads();
  if (t == 0) lpart[blockIdx.x] = wsum[0] + wsum[1] + wsum[2] + wsum[3];
}

// ------- kernel 7: loss = 1.25 * mean((q-x)^2) (UNCHANGED) -------
__global__ __launch_bounds__(256) void vq_loss(const float* __restrict__ lpart,
                                               float* __restrict__ out_loss) {
  __shared__ double dsum[4];
  const int t = threadIdx.x;
  double s = (double)lpart[t];
#pragma unroll
  for (int off = 32; off > 0; off >>= 1) s += __shfl_down(s, off, 64);
  if ((t & 63) == 0) dsum[t >> 6] = s;
  __syncthreads();
  if (t == 0) {
    const double total = dsum[0] + dsum[1] + dsum[2] + dsum[3];
    out_loss[0] = (float)(total * 1.25 / 4194304.0);
  }
}

extern "C" void kernel_launch(void* const* d_in, const int* in_sizes, int n_in,
                              void* d_out, int out_size, void* d_ws, size_t ws_size,
                              hipStream_t stream) {
  const float* x   = (const float*)d_in[0];   // [16,256,32,32]
  const float* emb = (const float*)d_in[1];   // [8192,256]
  float* out = (float*)d_out;
  float* ws  = (float*)d_ws;

  float*          xsq   = ws + WS_XSQ;
  float*          xT    = ws + WS_XT;
  unsigned short* xb    = (unsigned short*)(ws + WS_XB);
  unsigned short* eb    = (unsigned short*)(ws + WS_EB);
  __half*         tmax  = (__half*)(ws + WS_TMAX);
  int*            bestk = (int*)(ws + WS_BESTK);
  float*          lpart = ws + WS_LPART;

  float* out_q    = out;               // 4194304 floats
  float* out_loss = out + 4194304;     // 1 float
  float* out_idx  = out + 4194305;     // 16384 floats

  vq_x2<<<NROWS / 256, 256, 0, stream>>>(x, xsq);
  vq_cvt_x<<<dim3(16, 4, 16), 256, 0, stream>>>(x, xT, xb);
  vq_cvt_e<<<(KCB * DIM) / 1024, 256, 0, stream>>>(emb, eb);
  vq_coarse<<<(NROWS / 128) * (KCB / 128), 256, 0, stream>>>(xb, eb, tmax);
  vq_select<<<NROWS / 4, 256, 0, stream>>>(xT, emb, xsq, tmax, bestk, out_idx);
  vq_epi<<<NROWS / 64, 256, 0, stream>>>(x, emb, bestk, out_q, lpart);
  vq_loss<<<1, 256, 0, stream>>>(lpart, out_loss);
}